// Round 7
// baseline (938.031 us; speedup 1.0000x reference)
//
#include <hip/hip_runtime.h>
#include <hip/hip_cooperative_groups.h>

namespace cg = cooperative_groups;

// Problem constants: B,S,NODE,DEP,R,L,E = 32,1024,256,64,50,16,128
constexpr int B_ = 32;
constexpr int S_ = 1024;
constexpr int NODE_ = 256;
constexpr int DEP_ = 64;
constexpr int R_ = 50;
constexpr int L_ = 16;
constexpr int E_ = 128;
constexpr int FEAT_ = NODE_ + DEP_;     // 320
constexpr int NEDGE_ = B_ * E_;         // 4096 edges per layer
constexpr int BS_ = B_ * S_;            // 32768 rows
constexpr int CH_ = 16;                 // edges per relation-chunk
constexpr int NCH_ = 320;               // sum ceil(n_r/16) <= 306
constexpr int PREB_ = 512;              // worker blocks in k_pre
constexpr int GRID_ = 256;              // cooperative chain grid (1 block/CU)

// ---------------------------------------------------------------------------
// Algebra: msg = W[r][:,0:256]@ctx[t] + W[r][:,256:320]@childval[t].
// ctx term + index metadata precomputed (k_ctx, fully parallel), pre-scaled
// by 1/cnt[head] so accumulators A[] hold AVERAGES directly. Triple-buffered
// A: layer l scatters into A[l%3]; tails touched@l-1 resolve from A[(l-1)%3],
// else persistent child[]. The merge (A_prev rows -> child) and the clear of
// A[(l+1)%3] rows run inside the same grid segment (row-disjoint by
// construction). One cooperative kernel runs all 16 layers + output.
// ---------------------------------------------------------------------------
constexpr size_t N_CHILD  = (size_t)BS_ * DEP_;              // 2,097,152 floats
constexpr size_t OFF_A0   = N_CHILD;                         // A0,A1,A2 follow
constexpr size_t OFF_WT   = N_CHILD * 4;
constexpr size_t N_WT     = (size_t)R_ * FEAT_ * DEP_;       // 1,024,000
constexpr size_t OFF_SORT = OFF_WT + N_WT;
constexpr size_t N_SORT   = (size_t)L_ * NEDGE_;             // 65,536 ints
constexpr size_t OFF_CHUNK= OFF_SORT + N_SORT;
constexpr size_t N_CHUNK_I= (size_t)L_ * NCH_ * 4;           // ints
constexpr size_t OFF_HC   = OFF_CHUNK + N_CHUNK_I;
constexpr size_t N_HC     = (size_t)L_ * BS_;                // 524,288 ints
constexpr size_t OFF_MT   = OFF_HC + N_HC;                   // m_trow (tch in sign)
constexpr size_t OFF_MH   = OFF_MT + N_SORT;                 // m_hrow
constexpr size_t OFF_MI   = OFF_MH + N_SORT;                 // m_invc
constexpr size_t OFF_CD   = OFF_MI + N_SORT;                 // ctxdot
constexpr size_t N_CD     = (size_t)L_ * NEDGE_ * DEP_;      // 4,194,304

// ---------------------------------------------------------------------------
// K_PRE: blocks 0..15 = per-layer relation binning + chunk table + head-count
// hist; blocks 16.. = W re-layout WT2[r][i4][k][c] + zero child+A0.
// ---------------------------------------------------------------------------
__global__ void k_pre(const float* __restrict__ W, const int* __restrict__ rels,
                      const int* __restrict__ heads,
                      float* __restrict__ WT2, int* __restrict__ sorted,
                      int4* __restrict__ chunks, int* __restrict__ hc,
                      float* __restrict__ zero_base) {
  int blk = blockIdx.x, tid = threadIdx.x;
  if (blk < L_) {
    int l = blk;
    __shared__ int hist[R_], startA[R_], rank[R_], cstart[R_];
    __shared__ int ntot;
    if (tid < R_) { hist[tid] = 0; rank[tid] = 0; }
    int* hcl = hc + (size_t)l * BS_;
    for (int i = tid; i < BS_; i += 256) hcl[i] = 0;
    __syncthreads();
    for (int ed = tid; ed < NEDGE_; ed += 256) {
      int b = ed >> 7, e = ed & (E_ - 1);
      atomicAdd(&hist[rels[(b * L_ + l) * E_ + e]], 1);
      atomicAdd(&hcl[b * S_ + heads[(b * L_ + l) * E_ + e]], 1);
    }
    __syncthreads();
    if (tid == 0) {
      int s = 0, cs = 0;
      for (int r = 0; r < R_; ++r) {
        startA[r] = s; s += hist[r];
        cstart[r] = cs; cs += (hist[r] + CH_ - 1) / CH_;
      }
      ntot = cs;
    }
    __syncthreads();
    for (int ed = tid; ed < NEDGE_; ed += 256) {
      int b = ed >> 7, e = ed & (E_ - 1);
      int r = rels[(b * L_ + l) * E_ + e];
      int pos = startA[r] + atomicAdd(&rank[r], 1);
      sorted[l * NEDGE_ + pos] = ed;
    }
    if (tid < R_) {
      int n = hist[tid], st = startA[tid], cs = cstart[tid];
      for (int m = 0; m * CH_ < n; ++m) {
        int c = n - m * CH_; if (c > CH_) c = CH_;
        chunks[l * NCH_ + cs + m] = make_int4(tid, st + m * CH_, c, 0);
      }
    }
    __syncthreads();
    for (int i = ntot + tid; i < NCH_; i += 256)
      chunks[l * NCH_ + i] = make_int4(0, 0, 0, 0);
  } else {
    int gtid = (blk - L_) * 256 + tid;
    const int NT = PREB_ * 256;
    for (int gid = gtid; gid < (int)N_WT; gid += NT) {
      int r = gid / 20480;           // 80*64*4
      int rem = gid - r * 20480;
      int i4 = rem >> 8;
      int k = (rem >> 2) & 63;
      int c = rem & 3;
      WT2[gid] = W[((size_t)r * DEP_ + k) * FEAT_ + 4 * i4 + c];
    }
    float4* z4 = (float4*)zero_base;          // child + A0, contiguous
    int nz4 = (int)((N_CHILD * 2) / 4);
    for (int i = gtid; i < nz4; i += NT) z4[i] = make_float4(0.f, 0.f, 0.f, 0.f);
  }
}

// ---------------------------------------------------------------------------
// K_CTX: fully parallel. Per chunk: metadata (m_trow/m_hrow/m_invc) + the
// ctx-part dot, pre-scaled by invcnt. Feat rows are read via WAVE-UNIFORM
// (scalar-pipe) loads — no LDS staging, no feat broadcast through LDS.
// LDS used only for the 4-slice partial combine (~128 instrs/block).
// ---------------------------------------------------------------------------
__global__ void __launch_bounds__(256) k_ctx(
    const float* __restrict__ context, const float* __restrict__ WT2,
    const int* __restrict__ heads, const int* __restrict__ tails,
    const int* __restrict__ sorted, const int4* __restrict__ chunks,
    const int* __restrict__ hc, float* __restrict__ ctxdot,
    int* __restrict__ m_trow, int* __restrict__ m_hrow,
    float* __restrict__ m_invc) {
  int cid = blockIdx.x;
  int l = cid / NCH_;
  int4 ck = chunks[cid];
  int r = ck.x, start = ck.y, ccnt = ck.z;
  if (ccnt == 0) return;
  int tid = threadIdx.x, s = tid >> 6, k = tid & 63;

  __shared__ float part[4][CH_][DEP_];       // 16 KB
  __shared__ float invs[CH_];

  if (tid < ccnt) {
    int pos = l * NEDGE_ + start + tid;
    int ed = sorted[pos];
    int b = ed >> 7, e = ed & (E_ - 1);
    int t = tails[(b * L_ + l) * E_ + e];
    int h = heads[(b * L_ + l) * E_ + e];
    int trow = b * S_ + t, hrow = b * S_ + h;
    int tch = (l > 0) && (hc[(size_t)(l - 1) * BS_ + trow] > 0);
    float invc = 1.0f / (float)hc[(size_t)l * BS_ + hrow];   // >= 1
    m_trow[pos] = trow | (tch ? (int)0x80000000 : 0);
    m_hrow[pos] = hrow;
    m_invc[pos] = invc;
    invs[tid] = invc;
  }

  // W ctx-slice register cache (coalesced dwordx4)
  const float4* Wp = (const float4*)WT2 + ((size_t)r * 80 + s * 16) * 64 + k;
  float4 w[16];
#pragma unroll
  for (int i = 0; i < 16; ++i) w[i] = Wp[(size_t)i * 64];

  // wave s: dims [64s,64s+64) of all edges; feat via uniform scalar loads
#pragma unroll 4
  for (int j = 0; j < CH_; ++j) {
    int jc = (j < ccnt) ? j : (ccnt - 1);
    int pos = l * NEDGE_ + start + jc;
    int ed = __builtin_amdgcn_readfirstlane(sorted[pos]);
    int b = ed >> 7, e = ed & (E_ - 1);
    int t = __builtin_amdgcn_readfirstlane(tails[(b * L_ + l) * E_ + e]);
    const float4* fp =
        (const float4*)(context + ((size_t)(b * S_ + t)) * NODE_ + s * 64);
    float a0 = 0.f, a1 = 0.f, a2 = 0.f, a3 = 0.f;
#pragma unroll
    for (int i = 0; i < 16; ++i) {
      float4 f = fp[i];
      a0 = fmaf(w[i].x, f.x, a0);
      a1 = fmaf(w[i].y, f.y, a1);
      a2 = fmaf(w[i].z, f.z, a2);
      a3 = fmaf(w[i].w, f.w, a3);
    }
    part[s][jc][k] = (a0 + a1) + (a2 + a3);
  }
  __syncthreads();

  for (int idx = tid; idx < ccnt * DEP_; idx += 256) {
    int j = idx >> 6, k2 = idx & 63;
    ctxdot[(size_t)(l * NEDGE_ + start + j) * DEP_ + k2] =
        (part[0][j][k2] + part[1][j][k2] + part[2][j][k2] + part[3][j][k2]) *
        invs[j];
  }
}

// ---------------------------------------------------------------------------
// K_CHAIN: ONE cooperative kernel for all 16 layers + output pass.
// 256 blocks x 256 threads, no LDS, no __syncthreads — inter-layer ordering
// via grid.sync(). Per chunk: wave wv handles edges j=wv+4u; child rows read
// via wave-uniform loads; contribution = dot*invc + ctxdot, atomic into Acur.
// Then (row-disjoint) merge l-1 rows A_prev->child and clear A_next rows.
// ---------------------------------------------------------------------------
__global__ void __launch_bounds__(256) k_chain(
    const float* __restrict__ WT2, float* __restrict__ child,
    const int4* __restrict__ chunks, const int* __restrict__ m_trow,
    const int* __restrict__ m_hrow, const float* __restrict__ m_invc,
    const float* __restrict__ ctxdot, float* __restrict__ Abase,
    const int* __restrict__ hc15, const float4* __restrict__ ctx4,
    float4* __restrict__ out4) {
  cg::grid_group grid = cg::this_grid();
  int tid = threadIdx.x, wv = tid >> 6, k = tid & 63;

  for (int l = 0; l < L_; ++l) {
    float* Acur        = Abase + (size_t)(l % 3) * N_CHILD;
    const float* Aprev = Abase + (size_t)((l + 2) % 3) * N_CHILD;
    float* Anext       = Abase + (size_t)((l + 1) % 3) * N_CHILD;

    for (int cid = blockIdx.x; cid < NCH_; cid += gridDim.x) {
      int4 ck = chunks[l * NCH_ + cid];
      int r = ck.x, start = ck.y, ccnt = ck.z;
      if (ccnt == 0) continue;

      // W child-slice register cache (dims 256..320)
      const float4* Wp = (const float4*)WT2 + ((size_t)r * 80 + 64) * 64 + k;
      float4 w[16];
#pragma unroll
      for (int i = 0; i < 16; ++i) w[i] = Wp[(size_t)i * 64];

#pragma unroll
      for (int u = 0; u < 4; ++u) {
        int j = wv + 4 * u;
        bool valid = (j < ccnt);
        int jc = valid ? j : 0;
        int pos = l * NEDGE_ + start + jc;
        int tr = __builtin_amdgcn_readfirstlane(m_trow[pos]);
        int hrow = __builtin_amdgcn_readfirstlane(m_hrow[pos]);
        float invc = m_invc[pos];
        int trow = tr & 0x7fffffff;
        const float* base = (tr < 0) ? Aprev : child;   // uniform select
        const float4* fp = (const float4*)(base + (size_t)trow * DEP_);
        float a0 = 0.f, a1 = 0.f, a2 = 0.f, a3 = 0.f;
#pragma unroll
        for (int i = 0; i < 16; ++i) {
          float4 f = fp[i];
          a0 = fmaf(w[i].x, f.x, a0);
          a1 = fmaf(w[i].y, f.y, a1);
          a2 = fmaf(w[i].z, f.z, a2);
          a3 = fmaf(w[i].w, f.w, a3);
        }
        float d = (a0 + a1) + (a2 + a3);
        float contrib = d * invc + ctxdot[(size_t)pos * DEP_ + k];
        if (valid) atomicAdd(&Acur[(size_t)hrow * DEP_ + k], contrib);
      }
    }

    // Row-disjoint deferred phases (concurrent with other blocks' compute)
    int gtid = blockIdx.x * 256 + tid;
    const int NT = GRID_ * 256;
    if (l > 0) {
      const float4* Ap4 = (const float4*)Aprev;
      float4* ch4 = (float4*)child;
      const int* mh = m_hrow + (size_t)(l - 1) * NEDGE_;
      for (int idx = gtid; idx < NEDGE_ * 16; idx += NT) {
        int pos = idx >> 4, c4 = idx & 15;
        int hrow = mh[pos];
        ch4[(size_t)hrow * 16 + c4] = Ap4[(size_t)hrow * 16 + c4];
      }
    }
    if (l + 1 < L_) {
      float4* An4 = (float4*)Anext;
      const int* mh = m_hrow + (size_t)(l + 1) * NEDGE_;
      float4 z = make_float4(0.f, 0.f, 0.f, 0.f);
      for (int idx = gtid; idx < NEDGE_ * 16; idx += NT) {
        int pos = idx >> 4, c4 = idx & 15;
        An4[(size_t)mh[pos] * 16 + c4] = z;
      }
    }
    grid.sync();
  }

  // Output pass: layer-15 rows (hc15>0) read averages from A0, else child.
  constexpr int TOT4 = B_ * S_ * (FEAT_ / 4);
  const float4* A04 = (const float4*)Abase;   // A[15%3] = A0
  const float4* chd4 = (const float4*)child;
  for (int i = blockIdx.x * 256 + tid; i < TOT4; i += GRID_ * 256) {
    int row = i / 80;
    int c4 = i - row * 80;
    float4 v;
    if (c4 < 64) {
      v = ctx4[(size_t)row * 64 + c4];
    } else {
      int k4 = c4 - 64;
      v = (hc15[row] > 0) ? A04[(size_t)row * 16 + k4]
                          : chd4[(size_t)row * 16 + k4];
    }
    out4[i] = v;
  }
}

extern "C" void kernel_launch(void* const* d_in, const int* in_sizes, int n_in,
                              void* d_out, int out_size, void* d_ws, size_t ws_size,
                              hipStream_t stream) {
  const float* context = (const float*)d_in[0];
  const float* dep_W   = (const float*)d_in[1];
  const int*   heads   = (const int*)d_in[2];
  const int*   tails   = (const int*)d_in[3];
  const int*   rels    = (const int*)d_in[4];
  float* out = (float*)d_out;

  float* ws = (float*)d_ws;
  float* child  = ws;
  float* Abase  = ws + OFF_A0;
  float* WT2    = ws + OFF_WT;
  int*   sorted = (int*)(ws + OFF_SORT);
  int4*  chunks = (int4*)(ws + OFF_CHUNK);
  int*   hc     = (int*)(ws + OFF_HC);
  int*   m_trow = (int*)(ws + OFF_MT);
  int*   m_hrow = (int*)(ws + OFF_MH);
  float* m_invc = ws + OFF_MI;
  float* ctxdot = ws + OFF_CD;

  k_pre<<<L_ + PREB_, 256, 0, stream>>>(dep_W, rels, heads, WT2, sorted,
                                        chunks, hc, child);

  k_ctx<<<L_ * NCH_, 256, 0, stream>>>(context, WT2, heads, tails, sorted,
                                       chunks, hc, ctxdot, m_trow, m_hrow,
                                       m_invc);

  {
    const int4* chunks_c = chunks;
    const int* mt = m_trow; const int* mh = m_hrow;
    const float* mi = m_invc; const float* cd = ctxdot;
    const float* wt = WT2;
    const int* hc15 = hc + (size_t)(L_ - 1) * BS_;
    const float4* ctx4 = (const float4*)context;
    float4* out4 = (float4*)out;
    void* args[] = { (void*)&wt, (void*)&child, (void*)&chunks_c, (void*)&mt,
                     (void*)&mh, (void*)&mi, (void*)&cd, (void*)&Abase,
                     (void*)&hc15, (void*)&ctx4, (void*)&out4 };
    hipLaunchCooperativeKernel((const void*)k_chain, dim3(GRID_), dim3(256),
                               args, 0, stream);
  }
}

// Round 8
// 431.688 us; speedup vs baseline: 2.1729x; 2.1729x over previous
//
#include <hip/hip_runtime.h>

// Problem constants: B,S,NODE,DEP,R,L,E = 32,1024,256,64,50,16,128
constexpr int B_ = 32;
constexpr int S_ = 1024;
constexpr int NODE_ = 256;
constexpr int DEP_ = 64;
constexpr int R_ = 50;
constexpr int L_ = 16;
constexpr int E_ = 128;
constexpr int FEAT_ = NODE_ + DEP_;     // 320
constexpr int NEDGE_ = B_ * E_;         // 4096 edges per layer
constexpr int BS_ = B_ * S_;            // 32768 rows
constexpr int CH_ = 16;                 // edges per relation-chunk
constexpr int NCH_ = 320;               // sum ceil(n_r/16) <= 306
constexpr int PREB_ = 512;              // worker blocks in k_pre

// ---------------------------------------------------------------------------
// Algebra: msg = W[r][:,0:256]@ctx[t] + W[r][:,256:320]@childval[t].
// ctx term + index metadata precomputed (k_ctx, fully parallel), pre-scaled
// by 1/cnt[head] so accumulators A[] hold AVERAGES directly. Triple-buffered
// A: layer l scatters into A[l%3]; tails touched@l-1 resolve from A[(l-1)%3]
// (flag in m_trow sign bit), else persistent child[]. k_layer(l) also
// (row-disjoint, race-free) copies layer l-1 rows A_prev->child and zeroes
// A[(l+1)%3] rows for layer l+1. Stream-ordered launches are the layer
// barrier — cooperative grid.sync measured ~40µs/barrier here (round 7).
// ---------------------------------------------------------------------------
constexpr size_t N_CHILD  = (size_t)BS_ * DEP_;              // 2,097,152 floats
constexpr size_t OFF_A0   = N_CHILD;                         // A0,A1,A2 follow
constexpr size_t OFF_WT   = N_CHILD * 4;
constexpr size_t N_WT     = (size_t)R_ * FEAT_ * DEP_;       // 1,024,000
constexpr size_t OFF_SORT = OFF_WT + N_WT;
constexpr size_t N_SORT   = (size_t)L_ * NEDGE_;             // 65,536 ints
constexpr size_t OFF_CHUNK= OFF_SORT + N_SORT;
constexpr size_t N_CHUNK_I= (size_t)L_ * NCH_ * 4;           // ints
constexpr size_t OFF_HC   = OFF_CHUNK + N_CHUNK_I;
constexpr size_t N_HC     = (size_t)L_ * BS_;                // 524,288 ints
constexpr size_t OFF_MT   = OFF_HC + N_HC;                   // m_trow (tch in sign)
constexpr size_t OFF_MH   = OFF_MT + N_SORT;                 // m_hrow
constexpr size_t OFF_MI   = OFF_MH + N_SORT;                 // m_invc
constexpr size_t OFF_CD   = OFF_MI + N_SORT;                 // ctxdot
constexpr size_t N_CD     = (size_t)L_ * NEDGE_ * DEP_;      // 4,194,304

// ---------------------------------------------------------------------------
// K_PRE: blocks 0..15 = per-layer relation binning + chunk table + head-count
// hist; blocks 16.. = W re-layout WT2[r][i4][k][c] + zero child+A0.
// ---------------------------------------------------------------------------
__global__ void k_pre(const float* __restrict__ W, const int* __restrict__ rels,
                      const int* __restrict__ heads,
                      float* __restrict__ WT2, int* __restrict__ sorted,
                      int4* __restrict__ chunks, int* __restrict__ hc,
                      float* __restrict__ zero_base) {
  int blk = blockIdx.x, tid = threadIdx.x;
  if (blk < L_) {
    int l = blk;
    __shared__ int hist[R_], startA[R_], rank[R_], cstart[R_];
    __shared__ int ntot;
    if (tid < R_) { hist[tid] = 0; rank[tid] = 0; }
    int* hcl = hc + (size_t)l * BS_;
    for (int i = tid; i < BS_; i += 256) hcl[i] = 0;
    __syncthreads();
    for (int ed = tid; ed < NEDGE_; ed += 256) {
      int b = ed >> 7, e = ed & (E_ - 1);
      atomicAdd(&hist[rels[(b * L_ + l) * E_ + e]], 1);
      atomicAdd(&hcl[b * S_ + heads[(b * L_ + l) * E_ + e]], 1);
    }
    __syncthreads();
    if (tid == 0) {
      int s = 0, cs = 0;
      for (int r = 0; r < R_; ++r) {
        startA[r] = s; s += hist[r];
        cstart[r] = cs; cs += (hist[r] + CH_ - 1) / CH_;
      }
      ntot = cs;
    }
    __syncthreads();
    for (int ed = tid; ed < NEDGE_; ed += 256) {
      int b = ed >> 7, e = ed & (E_ - 1);
      int r = rels[(b * L_ + l) * E_ + e];
      int pos = startA[r] + atomicAdd(&rank[r], 1);
      sorted[l * NEDGE_ + pos] = ed;
    }
    if (tid < R_) {
      int n = hist[tid], st = startA[tid], cs = cstart[tid];
      for (int m = 0; m * CH_ < n; ++m) {
        int c = n - m * CH_; if (c > CH_) c = CH_;
        chunks[l * NCH_ + cs + m] = make_int4(tid, st + m * CH_, c, 0);
      }
    }
    __syncthreads();
    for (int i = ntot + tid; i < NCH_; i += 256)
      chunks[l * NCH_ + i] = make_int4(0, 0, 0, 0);
  } else {
    int gtid = (blk - L_) * 256 + tid;
    const int NT = PREB_ * 256;
    for (int gid = gtid; gid < (int)N_WT; gid += NT) {
      int r = gid / 20480;           // 80*64*4
      int rem = gid - r * 20480;
      int i4 = rem >> 8;
      int k = (rem >> 2) & 63;
      int c = rem & 3;
      WT2[gid] = W[((size_t)r * DEP_ + k) * FEAT_ + 4 * i4 + c];
    }
    float4* z4 = (float4*)zero_base;          // child + A0, contiguous
    int nz4 = (int)((N_CHILD * 2) / 4);
    for (int i = gtid; i < nz4; i += NT) z4[i] = make_float4(0.f, 0.f, 0.f, 0.f);
  }
}

// ---------------------------------------------------------------------------
// K_CTX: fully parallel. Per chunk: metadata (m_trow/m_hrow/m_invc) + the
// ctx-part dot, pre-scaled by invcnt. Feat rows read via WAVE-UNIFORM
// (scalar-pipe) loads — no LDS staging. LDS only for the 4-slice combine.
// ---------------------------------------------------------------------------
__global__ void __launch_bounds__(256) k_ctx(
    const float* __restrict__ context, const float* __restrict__ WT2,
    const int* __restrict__ heads, const int* __restrict__ tails,
    const int* __restrict__ sorted, const int4* __restrict__ chunks,
    const int* __restrict__ hc, float* __restrict__ ctxdot,
    int* __restrict__ m_trow, int* __restrict__ m_hrow,
    float* __restrict__ m_invc) {
  int cid = blockIdx.x;
  int l = cid / NCH_;
  int4 ck = chunks[cid];
  int r = ck.x, start = ck.y, ccnt = ck.z;
  if (ccnt == 0) return;
  int tid = threadIdx.x, s = tid >> 6, k = tid & 63;

  __shared__ float part[4][CH_][DEP_];       // 16 KB
  __shared__ float invs[CH_];

  if (tid < ccnt) {
    int pos = l * NEDGE_ + start + tid;
    int ed = sorted[pos];
    int b = ed >> 7, e = ed & (E_ - 1);
    int t = tails[(b * L_ + l) * E_ + e];
    int h = heads[(b * L_ + l) * E_ + e];
    int trow = b * S_ + t, hrow = b * S_ + h;
    int tch = (l > 0) && (hc[(size_t)(l - 1) * BS_ + trow] > 0);
    float invc = 1.0f / (float)hc[(size_t)l * BS_ + hrow];   // >= 1
    m_trow[pos] = trow | (tch ? (int)0x80000000 : 0);
    m_hrow[pos] = hrow;
    m_invc[pos] = invc;
    invs[tid] = invc;
  }

  // W ctx-slice register cache (coalesced dwordx4)
  const float4* Wp = (const float4*)WT2 + ((size_t)r * 80 + s * 16) * 64 + k;
  float4 w[16];
#pragma unroll
  for (int i = 0; i < 16; ++i) w[i] = Wp[(size_t)i * 64];

  // wave s: dims [64s,64s+64) of all edges; feat via uniform scalar loads
#pragma unroll 4
  for (int j = 0; j < CH_; ++j) {
    int jc = (j < ccnt) ? j : (ccnt - 1);
    int pos = l * NEDGE_ + start + jc;
    int ed = __builtin_amdgcn_readfirstlane(sorted[pos]);
    int b = ed >> 7, e = ed & (E_ - 1);
    int t = __builtin_amdgcn_readfirstlane(tails[(b * L_ + l) * E_ + e]);
    const float4* fp =
        (const float4*)(context + ((size_t)(b * S_ + t)) * NODE_ + s * 64);
    float a0 = 0.f, a1 = 0.f, a2 = 0.f, a3 = 0.f;
#pragma unroll
    for (int i = 0; i < 16; ++i) {
      float4 f = fp[i];
      a0 = fmaf(w[i].x, f.x, a0);
      a1 = fmaf(w[i].y, f.y, a1);
      a2 = fmaf(w[i].z, f.z, a2);
      a3 = fmaf(w[i].w, f.w, a3);
    }
    part[s][jc][k] = (a0 + a1) + (a2 + a3);
  }
  __syncthreads();

  for (int idx = tid; idx < ccnt * DEP_; idx += 256) {
    int j = idx >> 6, k2 = idx & 63;
    ctxdot[(size_t)(l * NEDGE_ + start + j) * DEP_ + k2] =
        (part[0][j][k2] + part[1][j][k2] + part[2][j][k2] + part[3][j][k2]) *
        invs[j];
  }
}

// ---------------------------------------------------------------------------
// K_LAYER: the serial-chain kernel — barrier-free, no LDS. Per chunk: wave wv
// handles edges j=wv+4u; child rows via wave-uniform loads (A_prev if touched
// @l-1 else child); contribution = dot*invc + ctxdot; atomic into Acur.
// Then row-disjoint: merge l-1 rows A_prev->child, clear A_next rows for l+1.
// ---------------------------------------------------------------------------
__global__ void __launch_bounds__(256) k_layer(
    const float* __restrict__ WT2, float* __restrict__ child,
    const int4* __restrict__ chunks, const int* __restrict__ m_trow,
    const int* __restrict__ m_hrow, const float* __restrict__ m_invc,
    const float* __restrict__ ctxdot, int l,
    const float* __restrict__ Aprev, float* __restrict__ Acur,
    float* __restrict__ Anext) {
  int tid = threadIdx.x, wv = tid >> 6, k = tid & 63;
  int4 ck = chunks[l * NCH_ + blockIdx.x];
  int r = ck.x, start = ck.y, ccnt = ck.z;

  if (ccnt > 0) {
    // W child-slice register cache (dims 256..320)
    const float4* Wp = (const float4*)WT2 + ((size_t)r * 80 + 64) * 64 + k;
    float4 w[16];
#pragma unroll
    for (int i = 0; i < 16; ++i) w[i] = Wp[(size_t)i * 64];

#pragma unroll
    for (int u = 0; u < 4; ++u) {
      int j = wv + 4 * u;
      bool valid = (j < ccnt);
      int jc = valid ? j : 0;
      int pos = l * NEDGE_ + start + jc;
      int tr = __builtin_amdgcn_readfirstlane(m_trow[pos]);
      int hrow = __builtin_amdgcn_readfirstlane(m_hrow[pos]);
      float invc = m_invc[pos];
      int trow = tr & 0x7fffffff;
      const float* base = (tr < 0) ? Aprev : child;   // uniform select
      const float4* fp = (const float4*)(base + (size_t)trow * DEP_);
      float a0 = 0.f, a1 = 0.f, a2 = 0.f, a3 = 0.f;
#pragma unroll
      for (int i = 0; i < 16; ++i) {
        float4 f = fp[i];
        a0 = fmaf(w[i].x, f.x, a0);
        a1 = fmaf(w[i].y, f.y, a1);
        a2 = fmaf(w[i].z, f.z, a2);
        a3 = fmaf(w[i].w, f.w, a3);
      }
      float d = (a0 + a1) + (a2 + a3);
      float contrib = d * invc + ctxdot[(size_t)pos * DEP_ + k];
      if (valid) atomicAdd(&Acur[(size_t)hrow * DEP_ + k], contrib);
    }
  }

  // Row-disjoint deferred phases
  int gtid = blockIdx.x * 256 + tid;
  const int NT = NCH_ * 256;
  if (l > 0) {
    const float4* Ap4 = (const float4*)Aprev;
    float4* ch4 = (float4*)child;
    const int* mh = m_hrow + (size_t)(l - 1) * NEDGE_;
    for (int idx = gtid; idx < NEDGE_ * 16; idx += NT) {
      int pos = idx >> 4, c4 = idx & 15;
      int hrow = mh[pos];
      ch4[(size_t)hrow * 16 + c4] = Ap4[(size_t)hrow * 16 + c4];
    }
  }
  if (l + 1 < L_) {
    float4* An4 = (float4*)Anext;
    const int* mh = m_hrow + (size_t)(l + 1) * NEDGE_;
    float4 z = make_float4(0.f, 0.f, 0.f, 0.f);
    for (int idx = gtid; idx < NEDGE_ * 16; idx += NT) {
      int pos = idx >> 4, c4 = idx & 15;
      An4[(size_t)mh[pos] * 16 + c4] = z;
    }
  }
}

// ---------------------------------------------------------------------------
// K_O: out = concat(context, childval); layer-15 rows read from A0 (averages).
// ---------------------------------------------------------------------------
__global__ void k_out(const float4* __restrict__ ctx4,
                      const float4* __restrict__ chd4,
                      const float4* __restrict__ A04,
                      const int* __restrict__ hc15,
                      float4* __restrict__ out4) {
  constexpr int TOT4 = B_ * S_ * (FEAT_ / 4);
  int i = blockIdx.x * blockDim.x + threadIdx.x;
  if (i >= TOT4) return;
  int row = i / 80;
  int c4 = i - row * 80;
  float4 v;
  if (c4 < 64) {
    v = ctx4[(size_t)row * 64 + c4];
  } else {
    int k4 = c4 - 64;
    v = (hc15[row] > 0) ? A04[(size_t)row * 16 + k4]
                        : chd4[(size_t)row * 16 + k4];
  }
  out4[i] = v;
}

extern "C" void kernel_launch(void* const* d_in, const int* in_sizes, int n_in,
                              void* d_out, int out_size, void* d_ws, size_t ws_size,
                              hipStream_t stream) {
  const float* context = (const float*)d_in[0];
  const float* dep_W   = (const float*)d_in[1];
  const int*   heads   = (const int*)d_in[2];
  const int*   tails   = (const int*)d_in[3];
  const int*   rels    = (const int*)d_in[4];
  float* out = (float*)d_out;

  float* ws = (float*)d_ws;
  float* child  = ws;
  float* A[3] = { ws + OFF_A0, ws + OFF_A0 + N_CHILD, ws + OFF_A0 + 2 * N_CHILD };
  float* WT2    = ws + OFF_WT;
  int*   sorted = (int*)(ws + OFF_SORT);
  int4*  chunks = (int4*)(ws + OFF_CHUNK);
  int*   hc     = (int*)(ws + OFF_HC);
  int*   m_trow = (int*)(ws + OFF_MT);
  int*   m_hrow = (int*)(ws + OFF_MH);
  float* m_invc = ws + OFF_MI;
  float* ctxdot = ws + OFF_CD;

  k_pre<<<L_ + PREB_, 256, 0, stream>>>(dep_W, rels, heads, WT2, sorted,
                                        chunks, hc, child);

  k_ctx<<<L_ * NCH_, 256, 0, stream>>>(context, WT2, heads, tails, sorted,
                                       chunks, hc, ctxdot, m_trow, m_hrow,
                                       m_invc);

  for (int l = 0; l < L_; ++l) {
    float* Acur  = A[l % 3];
    float* Aprev = A[(l + 2) % 3];
    float* Anext = A[(l + 1) % 3];
    k_layer<<<NCH_, 256, 0, stream>>>(WT2, child, chunks, m_trow, m_hrow,
                                      m_invc, ctxdot, l, Aprev, Acur, Anext);
  }

  constexpr int TOT4 = B_ * S_ * (FEAT_ / 4);
  k_out<<<(TOT4 + 255) / 256, 256, 0, stream>>>(
      (const float4*)context, (const float4*)child, (const float4*)A[0],
      hc + (size_t)(L_ - 1) * BS_, (float4*)out);
}